// Round 5
// baseline (2206.975 us; speedup 1.0000x reference)
//
#include <hip/hip_runtime.h>
#include <stdint.h>

// MultiheadAttention (separated projections), S=2048 B=4 E=1024 H=16 D=64.
// Outputs concatenated in d_out: out [S,B,E] fp32, attention [B,H,S,S] fp32.
// v5: v4 + XCD-bijective swizzle in fused attention (each XCD owns whole heads
// -> K/Vt fetched into exactly one L2) + nontemporal attention stores (don't
// thrash K/Vt L2 residency with the 1.07GB streaming write).
// Core: split-bf16 hi/lo 3-term MFMA; swapped-operand QK^T; register-resident P.
// ws: X hi/lo 33.6MB + W hi/lo 16.8MB + Q/K/Vt hi/lo 100.7MB = 151MB.

typedef __attribute__((ext_vector_type(8))) short bf16x8;
typedef __attribute__((ext_vector_type(4))) short bf16x4;
typedef __attribute__((ext_vector_type(4))) float f32x4;
typedef __attribute__((ext_vector_type(2))) unsigned u32x2;
typedef __attribute__((ext_vector_type(4))) unsigned u32x4;

#define DEV static __device__ __forceinline__

constexpr int S = 2048, B = 4, E = 1024, H = 16, D = 64;
constexpr int M1 = S * B;                 // 8192 projection rows
constexpr int NELEM = B * H * S * D;      // 8,388,608 elements per tensor
constexpr size_t OUT0 = (size_t)M1 * E;   // start of attention in d_out
constexpr float LOG2E = 1.44269504088896340736f;

DEV unsigned fbits(float x) { return __builtin_bit_cast(unsigned, x); }
DEV float bfhi(float x) {     // x truncated to bf16 precision, as fp32
  return __builtin_bit_cast(float, fbits(x) & 0xffff0000u);
}
DEV unsigned short f2bf(float f) {        // RNE
  unsigned u = fbits(f);
  u += 0x7fffu + ((u >> 16) & 1u);
  return (unsigned short)(u >> 16);
}
DEV float bf2f(unsigned short h) {
  return __builtin_bit_cast(float, ((unsigned)h) << 16);
}
DEV void splitT(float x, unsigned short& hi, unsigned short& lo) {  // RNE hi
  hi = f2bf(x);
  lo = (unsigned short)(fbits(x - bf2f(hi)) >> 16);
}
// pack {bf16(a) (low half), bf16(b) (high half)} by truncation, one v_perm
DEV unsigned packhi(float a, float b) {
  return __builtin_amdgcn_perm(fbits(b), fbits(a), 0x07060302u);
}

DEV f32x4 mfma32(bf16x8 a, bf16x8 b, f32x4 c) {
  return __builtin_amdgcn_mfma_f32_16x16x32_bf16(a, b, c, 0, 0, 0);
}
#if __has_builtin(__builtin_amdgcn_mfma_f32_16x16x16bf16_1k)
DEV f32x4 mfma16(bf16x4 a, bf16x4 b, f32x4 c) {
  return __builtin_amdgcn_mfma_f32_16x16x16bf16_1k(a, b, c, 0, 0, 0);
}
#else
// Fallback: widen K=16 frags to K=32 with zero-filled upper half. For x32,
// lane j-th element sits at k32 = lg*8 + j; zeros at j>=4 contribute nothing,
// and (lg, j<4) pairs cover each intended k16 = lg*4 + j exactly once in both
// operands simultaneously, so products pair up correctly.
DEV f32x4 mfma16(bf16x4 a, bf16x4 b, f32x4 c) {
  bf16x8 aw = {a[0], a[1], a[2], a[3], 0, 0, 0, 0};
  bf16x8 bw = {b[0], b[1], b[2], b[3], 0, 0, 0, 0};
  return __builtin_amdgcn_mfma_f32_16x16x32_bf16(aw, bw, c, 0, 0, 0);
}
#endif

#if __has_builtin(__builtin_nontemporal_store)
DEV void ntstore4(f32x4 v, float* p) { __builtin_nontemporal_store(v, (f32x4*)p); }
#else
DEV void ntstore4(f32x4 v, float* p) { *(f32x4*)p = v; }
#endif

// ---------------------------------------------------------------------------
// Prepass: split fp32 into bf16 hi (RNE) + lo (trunc of residual), 8/thread.
// ---------------------------------------------------------------------------
DEV void split8(const float* __restrict__ src, unsigned short* __restrict__ dh,
                unsigned short* __restrict__ dl, size_t i) {
  const float4 a = ((const float4*)src)[i * 2];
  const float4 b = ((const float4*)src)[i * 2 + 1];
  const float v[8] = {a.x, a.y, a.z, a.w, b.x, b.y, b.z, b.w};
  unsigned hb[8];
  float res[8];
#pragma unroll
  for (int j = 0; j < 8; ++j) {
    unsigned u = fbits(v[j]);
    unsigned ub = u + 0x7fffu + ((u >> 16) & 1u);   // RNE to bf16
    hb[j] = ub & 0xffff0000u;                        // hi as fp32 bits
    res[j] = v[j] - __builtin_bit_cast(float, hb[j]);
  }
  u32x4 hv, lv;
#pragma unroll
  for (int j = 0; j < 4; ++j) {
    hv[j] = __builtin_amdgcn_perm(hb[2 * j + 1], hb[2 * j], 0x07060302u);
    lv[j] = packhi(res[2 * j], res[2 * j + 1]);
  }
  *(u32x4*)(dh + i * 8) = hv;
  *(u32x4*)(dl + i * 8) = lv;
}

__global__ __launch_bounds__(256) void split_kernel(
    const float* __restrict__ src, unsigned short* __restrict__ dh,
    unsigned short* __restrict__ dl, int n8) {
  const int i = blockIdx.x * 256 + threadIdx.x;
  if (i < n8) split8(src, dh, dl, (size_t)i);
}

// 4 weight matrices in one launch; blockIdx.y selects tensor.
__global__ __launch_bounds__(256) void split4_kernel(
    const float* __restrict__ s0, const float* __restrict__ s1,
    const float* __restrict__ s2, const float* __restrict__ s3,
    unsigned short* __restrict__ dh, unsigned short* __restrict__ dl, int n8) {
  const int i = blockIdx.x * 256 + threadIdx.x;
  if (i >= n8) return;
  const int t = blockIdx.y;
  const float* src = (t == 0) ? s0 : (t == 1) ? s1 : (t == 2) ? s2 : s3;
  const size_t off = (size_t)t * n8 * 8;
  split8(src, dh + off, dl + off, (size_t)i);
}

// ---------------------------------------------------------------------------
// GEMM on pre-split operands: C[m,n] = sum_k A[m,k]*W[n,k] + bias[n], 3-term.
// MODE 0: Q proj -> hi/lo [B,H,S,D], scaled by (1/8)*log2(e). A rows = s*B+b.
// MODE 1: K proj -> hi/lo [B,H,S,D].
// MODE 2: V proj -> hi/lo transposed [B,H,D,S].
// MODE 3: out proj -> fp32 d_out [S,B,E] (A rows = b*S+s).
// 128x128 tile, BK=64, 4 waves (2x2); linear LDS (m97 structure).
// ---------------------------------------------------------------------------
template <int MODE>
__global__ __launch_bounds__(256) void gemm_kernel(
    const unsigned short* __restrict__ AhG, const unsigned short* __restrict__ AlG,
    const unsigned short* __restrict__ BhG, const unsigned short* __restrict__ BlG,
    const float* __restrict__ bias, unsigned short* __restrict__ outH,
    unsigned short* __restrict__ outL, float* __restrict__ outF) {
  __shared__ unsigned short Ah[128 * 64], Al[128 * 64];
  __shared__ unsigned short Bh[128 * 64], Bl[128 * 64];
  const int tid = threadIdx.x;
  const int lane = tid & 63, wave = tid >> 6;
  const int wr = wave >> 1, wc = wave & 1;
  const int lm = lane & 15, lg = lane >> 4;
  const int abase = blockIdx.x * 128;
  const int bbase = blockIdx.y * 128;
  const int srow = wave * 32 + (lane >> 3);   // +j*8
  const int scol = (lane & 7) * 8;            // halfword col within BK=64

  f32x4 acc[4][4] = {};

  for (int it = 0; it < E; it += 64) {
#pragma unroll
    for (int j = 0; j < 4; ++j) {
      const int row = srow + j * 8;
      const size_t ga = (size_t)(abase + row) * E + it + scol;
      const size_t gb = (size_t)(bbase + row) * E + it + scol;
      const int lidx = row * 64 + scol;
      *(u32x4*)&Ah[lidx] = *(const u32x4*)(AhG + ga);
      *(u32x4*)&Al[lidx] = *(const u32x4*)(AlG + ga);
      *(u32x4*)&Bh[lidx] = *(const u32x4*)(BhG + gb);
      *(u32x4*)&Bl[lidx] = *(const u32x4*)(BlG + gb);
    }
    __syncthreads();
#pragma unroll
    for (int kk = 0; kk < 2; ++kk) {
      const int hw = kk * 32 + lg * 8;
      bf16x8 ah[4], al[4], bh[4], bl[4];
#pragma unroll
      for (int m = 0; m < 4; ++m) {
        const int row = wr * 64 + m * 16 + lm;
        ah[m] = *(const bf16x8*)&Ah[row * 64 + hw];
        al[m] = *(const bf16x8*)&Al[row * 64 + hw];
      }
#pragma unroll
      for (int n = 0; n < 4; ++n) {
        const int row = wc * 64 + n * 16 + lm;
        bh[n] = *(const bf16x8*)&Bh[row * 64 + hw];
        bl[n] = *(const bf16x8*)&Bl[row * 64 + hw];
      }
#pragma unroll
      for (int m = 0; m < 4; ++m)
#pragma unroll
        for (int n = 0; n < 4; ++n) {
          acc[m][n] = mfma32(ah[m], bh[n], acc[m][n]);
          acc[m][n] = mfma32(ah[m], bl[n], acc[m][n]);
          acc[m][n] = mfma32(al[m], bh[n], acc[m][n]);
        }
    }
    __syncthreads();
  }

#pragma unroll
  for (int n = 0; n < 4; ++n) {
    const int gcol = bbase + wc * 64 + n * 16 + lm;
    const float bv = bias[gcol];
#pragma unroll
    for (int m = 0; m < 4; ++m) {
#pragma unroll
      for (int r = 0; r < 4; ++r) {
        const int grow = abase + wr * 64 + m * 16 + lg * 4 + r;
        float v = acc[m][n][r] + bv;
        if (MODE == 0) v *= 0.125f * LOG2E;  // fold 1/sqrt(D), log2e into Q
        if (MODE <= 2) {
          // input rows are s*B+b
          const int s = grow >> 2, b = grow & 3;
          const int h = gcol >> 6, d = gcol & 63;
          size_t idx;
          if (MODE == 2) idx = ((size_t)(b * H + h) * D + d) * S + s;   // V^T
          else           idx = ((size_t)(b * H + h) * S + s) * D + d;   // Q,K
          unsigned short hi, lo;
          splitT(v, hi, lo);
          outH[idx] = hi;
          outL[idx] = lo;
        } else {
          // A rows are b*S+s ; write out [S,B,E] fp32
          const int b = grow >> 11, s = grow & (S - 1);
          outF[(size_t)(s * B + b) * E + gcol] = v;
        }
      }
    }
  }
}

// ---------------------------------------------------------------------------
// Fused QK^T + softmax + attention-write + PV, q-tile 32, 1D grid of 4096.
// XCD-bijective swizzle: xcd = orig&7 owns heads [xcd*8, xcd*8+8) -> each
// head's K/Vt (1MB hi+lo) is fetched into exactly ONE XCD L2 and reused by
// all 64 q-blocks of that head. Attention stores are nontemporal so the
// 1.07GB streaming write doesn't evict the resident K/Vt.
// SWAPPED QK^T: acc[qh][n] = mfma32(Kfrag, Qfrag[qh]) -> lane (lg,lm) holds
// P[k = n0 + n*16 + lg*4 + r][q = qrow0 + qh*16 + lm]. Softmax over k: 64
// in-lane values + shfl_xor(16,32) + 8-wave LDS reduce; exp2 domain (log2e
// pre-folded into Q). PV: 16x16x16 B-frag layout (k = lg*4 + j, col = lm) ==
// accumulator layout, so P feeds PV from registers with zero exchange:
// y^T[d][q] += Vt (A) * P (B). Epilogue: cross-wave y reduce in LDS, write y
// pre-split bf16 hi/lo for the out-projection GEMM.
// ---------------------------------------------------------------------------
__global__ __launch_bounds__(512) void attn_pv_kernel(
    const unsigned short* __restrict__ Qh, const unsigned short* __restrict__ Ql,
    const unsigned short* __restrict__ Kh, const unsigned short* __restrict__ Kl,
    const unsigned short* __restrict__ Vth, const unsigned short* __restrict__ Vtl,
    float* __restrict__ attn, unsigned short* __restrict__ Yh,
    unsigned short* __restrict__ Yl) {
  __shared__ float red[2][8][32];
  __shared__ float ypart[8][32][68];   // +4 pad
  // bijective XCD swizzle (4096 % 8 == 0): XCD xcd gets fids [xcd*512, ..+512)
  // = heads [xcd*8, xcd*8+8), 64 consecutive q-blocks per head.
  const int orig = blockIdx.x;
  const int fid = (orig & 7) * 512 + (orig >> 3);
  const int bh = fid >> 6, qt = fid & 63;
  const int b = bh >> 4, h = bh & 15;
  const int tid = threadIdx.x, wave = tid >> 6, lane = tid & 63;
  const int lm = lane & 15, lg = lane >> 4;
  const int n0 = wave * 256, qrow0 = qt * 32;
  const size_t base = (size_t)bh * S * D;

  // Q fragments (B-operand), persistent: Q[q = qh*16+lm][d = kk*32 + lg*8 + j]
  bf16x8 qfh[2][2], qfl[2][2];
#pragma unroll
  for (int qh = 0; qh < 2; ++qh) {
    const size_t qoff = base + (size_t)(qrow0 + qh * 16 + lm) * D + lg * 8;
    qfh[qh][0] = *(const bf16x8*)(Qh + qoff);
    qfh[qh][1] = *(const bf16x8*)(Qh + qoff + 32);
    qfl[qh][0] = *(const bf16x8*)(Ql + qoff);
    qfl[qh][1] = *(const bf16x8*)(Ql + qoff + 32);
  }

  f32x4 acc[2][16];
#pragma unroll
  for (int qh = 0; qh < 2; ++qh)
#pragma unroll
    for (int n = 0; n < 16; ++n) acc[qh][n] = (f32x4){0.f, 0.f, 0.f, 0.f};

#pragma unroll
  for (int n = 0; n < 16; ++n) {
    const size_t koff = base + (size_t)(n0 + n * 16 + lm) * D + lg * 8;
#pragma unroll
    for (int kk = 0; kk < 2; ++kk) {
      bf16x8 kh = *(const bf16x8*)(Kh + koff + kk * 32);
      bf16x8 kl = *(const bf16x8*)(Kl + koff + kk * 32);
#pragma unroll
      for (int qh = 0; qh < 2; ++qh) {
        acc[qh][n] = mfma32(kh, qfh[qh][kk], acc[qh][n]);
        acc[qh][n] = mfma32(kh, qfl[qh][kk], acc[qh][n]);
        acc[qh][n] = mfma32(kl, qfh[qh][kk], acc[qh][n]);
      }
    }
  }

  // ---- softmax (per lane: q = qh*16 + lm, 64 k-values each) ----
#pragma unroll
  for (int qh = 0; qh < 2; ++qh) {
    float m = acc[qh][0][0];
#pragma unroll
    for (int n = 0; n < 16; ++n)
#pragma unroll
      for (int r = 0; r < 4; ++r) m = fmaxf(m, acc[qh][n][r]);
    m = fmaxf(m, __shfl_xor(m, 16));
    m = fmaxf(m, __shfl_xor(m, 32));
    if (lane < 16) red[0][wave][qh * 16 + lane] = m;
  }
  __syncthreads();
  float bm[2];
#pragma unroll
  for (int qh = 0; qh < 2; ++qh) {
    float m = red[0][0][qh * 16 + lm];
#pragma unroll
    for (int w = 1; w < 8; ++w) m = fmaxf(m, red[0][w][qh * 16 + lm]);
    bm[qh] = m;
  }
#pragma unroll
  for (int qh = 0; qh < 2; ++qh) {
    float sum = 0.f;
#pragma unroll
    for (int n = 0; n < 16; ++n)
#pragma unroll
      for (int r = 0; r < 4; ++r) {
        const float e = exp2f(acc[qh][n][r] - bm[qh]);
        acc[qh][n][r] = e;
        sum += e;
      }
    sum += __shfl_xor(sum, 16);
    sum += __shfl_xor(sum, 32);
    if (lane < 16) red[1][wave][qh * 16 + lane] = sum;
  }
  __syncthreads();
  float inv[2];
#pragma unroll
  for (int qh = 0; qh < 2; ++qh) {
    float bs = 0.f;
#pragma unroll
    for (int w = 0; w < 8; ++w) bs += red[1][w][qh * 16 + lm];
    inv[qh] = 1.0f / bs;
  }

  // ---- normalize, write attention (nontemporal), PV from registers ----
  const size_t vbase = (size_t)bh * D * S;
  float* outp0 = attn + (size_t)bh * S * S + (size_t)(qrow0 + lm) * S + n0 + lg * 4;
  f32x4 accy[2][4];
#pragma unroll
  for (int qh = 0; qh < 2; ++qh)
#pragma unroll
    for (int dn = 0; dn < 4; ++dn) accy[qh][dn] = (f32x4){0.f, 0.f, 0.f, 0.f};

#pragma unroll
  for (int n = 0; n < 16; ++n) {
    bf16x4 ph[2], pl[2];
#pragma unroll
    for (int qh = 0; qh < 2; ++qh) {
      acc[qh][n] *= inv[qh];
      ntstore4(acc[qh][n], outp0 + (size_t)qh * 16 * S + n * 16);
      const f32x4 a = acc[qh][n];
      const unsigned h0 = packhi(a[0], a[1]);
      const unsigned h1 = packhi(a[2], a[3]);
      const float l0 = a[0] - bfhi(a[0]);
      const float l1 = a[1] - bfhi(a[1]);
      const float l2 = a[2] - bfhi(a[2]);
      const float l3 = a[3] - bfhi(a[3]);
      ph[qh] = __builtin_bit_cast(bf16x4, (u32x2){h0, h1});
      pl[qh] = __builtin_bit_cast(bf16x4, (u32x2){packhi(l0, l1), packhi(l2, l3)});
    }
    const int koff = n0 + n * 16 + lg * 4;
#pragma unroll
    for (int dn = 0; dn < 4; ++dn) {
      const size_t vo = vbase + (size_t)(dn * 16 + lm) * S + koff;
      const bf16x4 vh = *(const bf16x4*)(Vth + vo);
      const bf16x4 vl = *(const bf16x4*)(Vtl + vo);
#pragma unroll
      for (int qh = 0; qh < 2; ++qh) {
        accy[qh][dn] = mfma16(vh, ph[qh], accy[qh][dn]);
        accy[qh][dn] = mfma16(vh, pl[qh], accy[qh][dn]);
        accy[qh][dn] = mfma16(vl, ph[qh], accy[qh][dn]);
      }
    }
  }

  // ---- cross-wave y reduce: lane holds y[q = qh*16+lm][d = dn*16 + lg*4 + r]
#pragma unroll
  for (int qh = 0; qh < 2; ++qh)
#pragma unroll
    for (int dn = 0; dn < 4; ++dn)
      *(f32x4*)&ypart[wave][qh * 16 + lm][dn * 16 + lg * 4] = accy[qh][dn];
  __syncthreads();
  for (int e = tid; e < 2048; e += 512) {
    const int q = e >> 6, d = e & 63;
    float s = 0.f;
#pragma unroll
    for (int w = 0; w < 8; ++w) s += ypart[w][q][d];
    unsigned short hi, lo;
    splitT(s, hi, lo);
    const size_t idx = ((size_t)(b * S + qrow0 + q)) * E + h * 64 + d;
    Yh[idx] = hi;
    Yl[idx] = lo;
  }
}

// ---------------------------------------------------------------------------
extern "C" void kernel_launch(void* const* d_in, const int* in_sizes, int n_in,
                              void* d_out, int out_size, void* d_ws,
                              size_t ws_size, hipStream_t stream) {
  (void)in_sizes; (void)n_in; (void)out_size; (void)ws_size;
  const float* query = (const float*)d_in[0];
  const float* key   = (const float*)d_in[1];
  const float* value = (const float*)d_in[2];
  const float* Wq = (const float*)d_in[3];
  const float* bq = (const float*)d_in[4];
  const float* Wk = (const float*)d_in[5];
  const float* bk = (const float*)d_in[6];
  const float* Wv = (const float*)d_in[7];
  const float* bv = (const float*)d_in[8];
  const float* Wo = (const float*)d_in[9];
  const float* bo = (const float*)d_in[10];

  float* out = (float*)d_out;
  float* attn = out + OUT0;

  // ws layout (ushort units): X hi/lo (reused q/k/v; aliased by Y) |
  // WHall/WLall (4 tensors each) | Qh Ql Kh Kl Vth Vtl.  Total 151 MB.
  unsigned short* p = (unsigned short*)d_ws;
  unsigned short* XH = p; p += NELEM;
  unsigned short* XL = p; p += NELEM;
  unsigned short* WHall = p; p += 4 * E * E;
  unsigned short* WLall = p; p += 4 * E * E;
  unsigned short* QH = p;  p += NELEM;
  unsigned short* QL = p;  p += NELEM;
  unsigned short* KH = p;  p += NELEM;
  unsigned short* KL = p;  p += NELEM;
  unsigned short* VTH = p; p += NELEM;
  unsigned short* VTL = p; p += NELEM;
  unsigned short* YH = XH;   // alias: X dead after gemm<2>, Y born after
  unsigned short* YL = XL;

  const int wn8 = E * E / 8, xn8 = NELEM / 8;
  split4_kernel<<<dim3(wn8 / 256, 4), 256, 0, stream>>>(Wq, Wk, Wv, Wo, WHall,
                                                        WLall, wn8);

  const dim3 gproj(M1 / 128, E / 128);  // 64 x 8
  split_kernel<<<xn8 / 256, 256, 0, stream>>>(query, XH, XL, xn8);
  gemm_kernel<0><<<gproj, 256, 0, stream>>>(XH, XL, WHall + 0 * E * E,
                                            WLall + 0 * E * E, bq, QH, QL,
                                            nullptr);
  split_kernel<<<xn8 / 256, 256, 0, stream>>>(key, XH, XL, xn8);
  gemm_kernel<1><<<gproj, 256, 0, stream>>>(XH, XL, WHall + 1 * E * E,
                                            WLall + 1 * E * E, bk, KH, KL,
                                            nullptr);
  split_kernel<<<xn8 / 256, 256, 0, stream>>>(value, XH, XL, xn8);
  gemm_kernel<2><<<gproj, 256, 0, stream>>>(XH, XL, WHall + 2 * E * E,
                                            WLall + 2 * E * E, bv, VTH, VTL,
                                            nullptr);

  attn_pv_kernel<<<dim3(S / 32 * B * H), 512, 0, stream>>>(QH, QL, KH, KL,
                                                           VTH, VTL, attn, YH,
                                                           YL);
  gemm_kernel<3><<<gproj, 256, 0, stream>>>(YH, YL, WHall + 3 * E * E,
                                            WLall + 3 * E * E, bo, nullptr,
                                            nullptr, out);
}